// Round 2
// baseline (321.765 us; speedup 1.0000x reference)
//
#include <hip/hip_runtime.h>

#define N_ 2048
#define BN 16384
#define IN_DIM 320
#define QKV_N 1536
#define NEG_INF -1e9f

typedef float f32x4 __attribute__((ext_vector_type(4)));
typedef short v8s __attribute__((ext_vector_type(8)));

__device__ __forceinline__ short f2b(float f) {
  unsigned u = __builtin_bit_cast(unsigned, f);
  u = u + 0x7fff + ((u >> 16) & 1);
  return (short)(u >> 16);
}

// ---------------- Kernel 1: build x = [data | mask | time-embedding] (fp32 in -> bf16 out) ----
__global__ void build_x(const float* __restrict__ times, const float* __restrict__ data,
                        const float* __restrict__ maskv, const float* __restrict__ w_per,
                        const float* __restrict__ b_per, const float* __restrict__ w_lin,
                        const float* __restrict__ b_lin, short* __restrict__ x) {
  int row = blockIdx.x;       // 0..16383
  int t = threadIdx.x;        // 128 threads
  float tt = times[row];
  short* xr = x + (size_t)row * IN_DIM;
  const float* dr = data + (size_t)row * 96;
  const float* mr = maskv + (size_t)row * 96;
  if (t < 96) { xr[t] = f2b(dr[t]); xr[96 + t] = f2b(mr[t]); }
  float val;
  if (t == 0) val = tt * w_lin[0] + b_lin[0];
  else        val = __sinf(tt * w_per[t - 1] + b_per[t - 1]);
  xr[192 + t] = f2b(val);
}

// ---------------- Kernel 2: transpose weights (fp32 -> bf16) ----------------
__global__ void transpose_w(const float* __restrict__ Wq, const float* __restrict__ Wk,
                            const float* __restrict__ Wv, const float* __restrict__ Wfc,
                            short* __restrict__ Wt, short* __restrict__ WfcT) {
  int idx = blockIdx.x * 256 + threadIdx.x;
  if (idx < QKV_N * IN_DIM) {
    int n = idx / IN_DIM, kk = idx - n * IN_DIM;
    const float* W = (n < 512) ? Wq : (n < 1024 ? Wk : Wv);
    Wt[idx] = f2b(W[(size_t)kk * 512 + (n & 511)]);
  } else {
    int j = idx - QKV_N * IN_DIM;   // 0..32767
    int d = j >> 9, kk = j & 511;
    WfcT[j] = f2b(Wfc[kk * 64 + d]);
  }
}

// ---------------- Kernel 3: QKV GEMM (M=16384, N=1536, K=320) ----------------
__launch_bounds__(256)
__global__ void qkv_gemm(const short* __restrict__ x, const short* __restrict__ Wt,
                         const float* __restrict__ bq, const float* __restrict__ bk,
                         const float* __restrict__ bv,
                         short* __restrict__ q, short* __restrict__ k, short* __restrict__ v) {
  __shared__ short As[128][40];
  __shared__ short Bs[128][40];
  int bm = blockIdx.x;   // 0..127
  int bn = blockIdx.y;   // 0..11
  int tid = threadIdx.x, wave = tid >> 6, lane = tid & 63;
  int wm = wave >> 1, wn = wave & 1;
  int l16 = lane & 15, lh = lane >> 4;
  f32x4 acc[4][4] = {};
  for (int kt = 0; kt < 10; ++kt) {
    int k0 = kt * 32;
#pragma unroll
    for (int s = 0; s < 2; ++s) {
      int c = tid + s * 256;          // 512 16B-chunks
      int r = c >> 2, c8 = c & 3;
      *(v8s*)&As[r][c8 * 8] = *(const v8s*)&x[(size_t)(bm * 128 + r) * IN_DIM + k0 + c8 * 8];
      *(v8s*)&Bs[r][c8 * 8] = *(const v8s*)&Wt[(size_t)(bn * 128 + r) * IN_DIM + k0 + c8 * 8];
    }
    __syncthreads();
    v8s af[4], bfr[4];
#pragma unroll
    for (int m = 0; m < 4; ++m) af[m] = *(const v8s*)&As[wm * 64 + m * 16 + l16][lh * 8];
#pragma unroll
    for (int n = 0; n < 4; ++n) bfr[n] = *(const v8s*)&Bs[wn * 64 + n * 16 + l16][lh * 8];
#pragma unroll
    for (int m = 0; m < 4; ++m)
#pragma unroll
      for (int n = 0; n < 4; ++n)
        acc[m][n] = __builtin_amdgcn_mfma_f32_16x16x32_bf16(af[m], bfr[n], acc[m][n], 0, 0, 0);
    __syncthreads();
  }
  // epilogue: bias + scatter into q/k/v [b][h][n][d]
#pragma unroll
  for (int m = 0; m < 4; ++m) {
    int row0 = bm * 128 + wm * 64 + m * 16 + lh * 4;
#pragma unroll
    for (int n = 0; n < 4; ++n) {
      int col = bn * 128 + wn * 64 + n * 16 + l16;   // 0..1535
      int w = col >> 9, c = col & 511;
      const float* bias = (w == 0) ? bq : ((w == 1) ? bk : bv);
      short* dst = (w == 0) ? q : ((w == 1) ? k : v);
      float bb = bias[c];
      int h = c >> 6, d = c & 63;
#pragma unroll
      for (int r = 0; r < 4; ++r) {
        int rr = row0 + r;
        int b = rr >> 11, ntok = rr & 2047;
        dst[(((size_t)(b * 8 + h) * N_ + ntok) << 6) + d] = f2b(acc[m][n][r] + bb);
      }
    }
  }
}

// ---------------- Kernel 4: flash attention ----------------
__launch_bounds__(256)
__global__ void attn_kernel(const short* __restrict__ q, const short* __restrict__ k,
                            const short* __restrict__ v, const int* __restrict__ exist,
                            short* __restrict__ att) {
  __shared__ short Ks[64][72];
  __shared__ short VTs[64][72];
  __shared__ short Ps[128][72];
  __shared__ float Mflag[64];
  int bh = blockIdx.y, b = bh >> 3, h = bh & 7;
  int q0 = blockIdx.x * 128;
  int tid = threadIdx.x, wave = tid >> 6, lane = tid & 63;
  int l16 = lane & 15, lh = lane >> 4;
  const short* qp = q + (size_t)bh * N_ * 64;
  const short* kp = k + (size_t)bh * N_ * 64;
  const short* vp = v + (size_t)bh * N_ * 64;
  const int* ex = exist + b * N_;
  v8s qf[2][2];
#pragma unroll
  for (int m = 0; m < 2; ++m)
#pragma unroll
    for (int kc = 0; kc < 2; ++kc)
      qf[m][kc] = *(const v8s*)&qp[(size_t)(q0 + wave * 32 + m * 16 + l16) * 64 + kc * 32 + lh * 8];
  f32x4 oacc[2][4] = {};
  float mrun[2][4], lrun[2][4];
#pragma unroll
  for (int m = 0; m < 2; ++m)
#pragma unroll
    for (int r = 0; r < 4; ++r) { mrun[m][r] = -3e38f; lrun[m][r] = 0.f; }
  const float scale = 0.05590169943749474f;   // 1/sqrt(320)
  for (int kt = 0; kt < N_ / 64; ++kt) {
    int kv0 = kt * 64;
#pragma unroll
    for (int s = 0; s < 2; ++s) {
      int c = tid + s * 256;
      int cr = c >> 3, cc = c & 7;
      *(v8s*)&Ks[cr][cc * 8] = *(const v8s*)&kp[(size_t)(kv0 + cr) * 64 + cc * 8];
      v8s vv = *(const v8s*)&vp[(size_t)(kv0 + cr) * 64 + cc * 8];
#pragma unroll
      for (int i = 0; i < 8; ++i) VTs[cc * 8 + i][cr] = vv[i];
    }
    if (tid < 64) Mflag[tid] = (ex[kv0 + tid] != 0) ? 1.f : 0.f;
    __syncthreads();
    // S = q @ k^T
    f32x4 sacc[2][4] = {};
#pragma unroll
    for (int kc = 0; kc < 2; ++kc)
#pragma unroll
      for (int n = 0; n < 4; ++n) {
        v8s kf = *(const v8s*)&Ks[n * 16 + l16][kc * 32 + lh * 8];
#pragma unroll
        for (int m = 0; m < 2; ++m)
          sacc[m][n] = __builtin_amdgcn_mfma_f32_16x16x32_bf16(qf[m][kc], kf, sacc[m][n], 0, 0, 0);
      }
    // online softmax
    float flag[4];
#pragma unroll
    for (int n = 0; n < 4; ++n) flag[n] = Mflag[n * 16 + l16];
#pragma unroll
    for (int m = 0; m < 2; ++m) {
#pragma unroll
      for (int r = 0; r < 4; ++r) {
        float sv[4];
        float rmax = -3e38f;
#pragma unroll
        for (int n = 0; n < 4; ++n) {
          float s0 = sacc[m][n][r] * scale;
          s0 = (flag[n] != 0.f) ? s0 : NEG_INF;   // exact replacement like jnp.where
          sv[n] = s0;
          rmax = fmaxf(rmax, s0);
        }
#pragma unroll
        for (int off = 1; off < 16; off <<= 1)
          rmax = fmaxf(rmax, __shfl_xor(rmax, off, 16));
        float mnew = fmaxf(mrun[m][r], rmax);
        float corr = __expf(mrun[m][r] - mnew);
        float psum = 0.f;
#pragma unroll
        for (int n = 0; n < 4; ++n) {
          float p = __expf(sv[n] - mnew);
          psum += p;
          Ps[wave * 32 + m * 16 + lh * 4 + r][n * 16 + l16] = f2b(p);
        }
#pragma unroll
        for (int off = 1; off < 16; off <<= 1)
          psum += __shfl_xor(psum, off, 16);
        lrun[m][r] = lrun[m][r] * corr + psum;
        mrun[m][r] = mnew;
#pragma unroll
        for (int n = 0; n < 4; ++n) oacc[m][n][r] *= corr;
      }
    }
    // O += P @ V   (per-wave Ps region: same-wave LDS ops are ordered, no barrier needed)
#pragma unroll
    for (int kc = 0; kc < 2; ++kc) {
      v8s pf[2];
#pragma unroll
      for (int m = 0; m < 2; ++m)
        pf[m] = *(const v8s*)&Ps[wave * 32 + m * 16 + l16][kc * 32 + lh * 8];
#pragma unroll
      for (int n = 0; n < 4; ++n) {
        v8s vf = *(const v8s*)&VTs[n * 16 + l16][kc * 32 + lh * 8];
#pragma unroll
        for (int m = 0; m < 2; ++m)
          oacc[m][n] = __builtin_amdgcn_mfma_f32_16x16x32_bf16(pf[m], vf, oacc[m][n], 0, 0, 0);
      }
    }
    __syncthreads();
  }
  // epilogue: normalize, query-mask, write att[b][n][h*64+d] (bf16)
#pragma unroll
  for (int m = 0; m < 2; ++m)
#pragma unroll
    for (int r = 0; r < 4; ++r) {
      int row = q0 + wave * 32 + m * 16 + lh * 4 + r;
      float qm = (ex[row] != 0) ? 1.f : 0.f;
      float inv = qm / lrun[m][r];
#pragma unroll
      for (int n = 0; n < 4; ++n)
        att[((size_t)(b * N_ + row)) * 512 + h * 64 + n * 16 + l16] = f2b(oacc[m][n][r] * inv);
    }
}

// ---------------- Kernel 5: out = att @ Wfc + bfc (M=16384, N=64, K=512), fp32 out ----------
__launch_bounds__(256)
__global__ void out_gemm(const short* __restrict__ att, const short* __restrict__ WfcT,
                         const float* __restrict__ bfc, float* __restrict__ out) {
  __shared__ short As[128][40];
  __shared__ short Bs[64][40];
  int bm = blockIdx.x;
  int tid = threadIdx.x, wave = tid >> 6, lane = tid & 63;
  int l16 = lane & 15, lh = lane >> 4;
  f32x4 acc[2][4] = {};
  for (int kt = 0; kt < 16; ++kt) {
    int k0 = kt * 32;
#pragma unroll
    for (int s = 0; s < 2; ++s) {
      int c = tid + s * 256;
      int r = c >> 2, c8 = c & 3;
      *(v8s*)&As[r][c8 * 8] = *(const v8s*)&att[(size_t)(bm * 128 + r) * 512 + k0 + c8 * 8];
    }
    { int r = tid >> 2, c8 = tid & 3;
      if (r < 64) *(v8s*)&Bs[r][c8 * 8] = *(const v8s*)&WfcT[(size_t)r * 512 + k0 + c8 * 8]; }
    __syncthreads();
    v8s bfr[4];
#pragma unroll
    for (int n = 0; n < 4; ++n) bfr[n] = *(const v8s*)&Bs[n * 16 + l16][lh * 8];
#pragma unroll
    for (int m = 0; m < 2; ++m) {
      v8s af = *(const v8s*)&As[wave * 32 + m * 16 + l16][lh * 8];
#pragma unroll
      for (int n = 0; n < 4; ++n)
        acc[m][n] = __builtin_amdgcn_mfma_f32_16x16x32_bf16(af, bfr[n], acc[m][n], 0, 0, 0);
    }
    __syncthreads();
  }
#pragma unroll
  for (int m = 0; m < 2; ++m)
#pragma unroll
    for (int n = 0; n < 4; ++n) {
      float bb = bfc[n * 16 + l16];
#pragma unroll
      for (int r = 0; r < 4; ++r) {
        int row = bm * 128 + wave * 32 + m * 16 + lh * 4 + r;
        out[(size_t)row * 64 + n * 16 + l16] = acc[m][n][r] + bb;
      }
    }
}

extern "C" void kernel_launch(void* const* d_in, const int* in_sizes, int n_in,
                              void* d_out, int out_size, void* d_ws, size_t ws_size,
                              hipStream_t stream) {
  const float* times = (const float*)d_in[0];
  const float* data  = (const float*)d_in[1];
  const float* maskv = (const float*)d_in[2];
  const int*   exist = (const int*)d_in[3];
  const float* w_per = (const float*)d_in[4];
  const float* b_per = (const float*)d_in[5];
  const float* w_lin = (const float*)d_in[6];
  const float* b_lin = (const float*)d_in[7];
  const float* Wq  = (const float*)d_in[8];
  const float* bq  = (const float*)d_in[9];
  const float* Wk  = (const float*)d_in[10];
  const float* bk  = (const float*)d_in[11];
  const float* Wv  = (const float*)d_in[12];
  const float* bv  = (const float*)d_in[13];
  const float* Wfc = (const float*)d_in[14];
  const float* bfc = (const float*)d_in[15];
  float* out = (float*)d_out;

  char* ws = (char*)d_ws;
  short* x    = (short*)(ws);                    // 16384*320*2  = 10,485,760
  short* Wt   = (short*)(ws + 10485760);         // 1536*320*2   =    983,040
  short* WfcT = (short*)(ws + 11468800);         // 64*512*2     =     65,536
  short* qb   = (short*)(ws + 11534336);         // 64*2048*64*2 = 16,777,216
  short* kb   = (short*)(ws + 28311552);
  short* vb   = (short*)(ws + 45088768);
  short* att  = (short*)(ws + 61865984);         // 16384*512*2  = 16,777,216

  build_x<<<BN, 128, 0, stream>>>(times, data, maskv, w_per, b_per, w_lin, b_lin, x);
  transpose_w<<<2048, 256, 0, stream>>>(Wq, Wk, Wv, Wfc, Wt, WfcT);
  qkv_gemm<<<dim3(128, 12), 256, 0, stream>>>(x, Wt, bq, bk, bv, qb, kb, vb);
  attn_kernel<<<dim3(16, 64), 256, 0, stream>>>(qb, kb, vb, exist, att);
  out_gemm<<<128, 256, 0, stream>>>(att, WfcT, bfc, out);
}

// Round 3
// 174.846 us; speedup vs baseline: 1.8403x; 1.8403x over previous
//
#include <hip/hip_runtime.h>

#define N_ 2048
#define BN 16384
#define IN_DIM 320
#define QKV_N 1536
// (1/sqrt(320)) * log2(e): folded into Q so QK^T scores are base-2 exponents
#define ALPHA 0.08064911f

typedef float f32x4 __attribute__((ext_vector_type(4)));
typedef short v8s __attribute__((ext_vector_type(8)));
typedef unsigned int u32x2 __attribute__((ext_vector_type(2)));

__device__ __forceinline__ short f2b(float f) {
  unsigned u = __builtin_bit_cast(unsigned, f);
  u = u + 0x7fff + ((u >> 16) & 1);
  return (short)(u >> 16);
}

// ---------------- Kernel 1: build x = [data | mask | time-embedding] ----------------
__global__ void build_x(const float* __restrict__ times, const float* __restrict__ data,
                        const float* __restrict__ maskv, const float* __restrict__ w_per,
                        const float* __restrict__ b_per, const float* __restrict__ w_lin,
                        const float* __restrict__ b_lin, short* __restrict__ x) {
  int row = blockIdx.x;       // 0..16383
  int t = threadIdx.x;        // 128 threads
  float tt = times[row];
  short* xr = x + (size_t)row * IN_DIM;
  const float* dr = data + (size_t)row * 96;
  const float* mr = maskv + (size_t)row * 96;
  if (t < 96) { xr[t] = f2b(dr[t]); xr[96 + t] = f2b(mr[t]); }
  float val;
  if (t == 0) val = tt * w_lin[0] + b_lin[0];
  else        val = __sinf(tt * w_per[t - 1] + b_per[t - 1]);
  xr[192 + t] = f2b(val);
}

// ---------------- Kernel 2: transpose weights (fp32 -> bf16) ----------------
__global__ void transpose_w(const float* __restrict__ Wq, const float* __restrict__ Wk,
                            const float* __restrict__ Wv, const float* __restrict__ Wfc,
                            short* __restrict__ Wt, short* __restrict__ WfcT) {
  int idx = blockIdx.x * 256 + threadIdx.x;
  if (idx < QKV_N * IN_DIM) {
    int n = idx / IN_DIM, kk = idx - n * IN_DIM;
    const float* W = (n < 512) ? Wq : (n < 1024 ? Wk : Wv);
    Wt[idx] = f2b(W[(size_t)kk * 512 + (n & 511)]);
  } else {
    int j = idx - QKV_N * IN_DIM;   // 0..32767
    int d = j >> 9, kk = j & 511;
    WfcT[j] = f2b(Wfc[kk * 64 + d]);
  }
}

// ---------------- Kernel 3: QKV GEMM (M=16384, N=1536, K=320) ----------------
__launch_bounds__(256)
__global__ void qkv_gemm(const short* __restrict__ x, const short* __restrict__ Wt,
                         const float* __restrict__ bq, const float* __restrict__ bk,
                         const float* __restrict__ bv,
                         short* __restrict__ q, short* __restrict__ k, short* __restrict__ v) {
  __shared__ short As[128][40];
  __shared__ short Bs[128][40];
  int bm = blockIdx.x;   // 0..127
  int bn = blockIdx.y;   // 0..11
  int tid = threadIdx.x, wave = tid >> 6, lane = tid & 63;
  int wm = wave >> 1, wn = wave & 1;
  int l16 = lane & 15, lh = lane >> 4;
  f32x4 acc[4][4] = {};
  for (int kt = 0; kt < 10; ++kt) {
    int k0 = kt * 32;
#pragma unroll
    for (int s = 0; s < 2; ++s) {
      int c = tid + s * 256;          // 512 16B-chunks
      int r = c >> 2, c8 = c & 3;
      *(v8s*)&As[r][c8 * 8] = *(const v8s*)&x[(size_t)(bm * 128 + r) * IN_DIM + k0 + c8 * 8];
      *(v8s*)&Bs[r][c8 * 8] = *(const v8s*)&Wt[(size_t)(bn * 128 + r) * IN_DIM + k0 + c8 * 8];
    }
    __syncthreads();
    v8s af[4], bfr[4];
#pragma unroll
    for (int m = 0; m < 4; ++m) af[m] = *(const v8s*)&As[wm * 64 + m * 16 + l16][lh * 8];
#pragma unroll
    for (int n = 0; n < 4; ++n) bfr[n] = *(const v8s*)&Bs[wn * 64 + n * 16 + l16][lh * 8];
#pragma unroll
    for (int m = 0; m < 4; ++m)
#pragma unroll
      for (int n = 0; n < 4; ++n)
        acc[m][n] = __builtin_amdgcn_mfma_f32_16x16x32_bf16(af[m], bfr[n], acc[m][n], 0, 0, 0);
    __syncthreads();
  }
  // epilogue: bias (+ALPHA fold for Q) + scatter into q/k/v [b][h][n][d]
#pragma unroll
  for (int m = 0; m < 4; ++m) {
    int row0 = bm * 128 + wm * 64 + m * 16 + lh * 4;
#pragma unroll
    for (int n = 0; n < 4; ++n) {
      int col = bn * 128 + wn * 64 + n * 16 + l16;   // 0..1535
      int w = col >> 9, c = col & 511;
      const float* bias = (w == 0) ? bq : ((w == 1) ? bk : bv);
      short* dst = (w == 0) ? q : ((w == 1) ? k : v);
      float bb = bias[c];
      float scl = (w == 0) ? ALPHA : 1.0f;
      int h = c >> 6, d = c & 63;
#pragma unroll
      for (int r = 0; r < 4; ++r) {
        int rr = row0 + r;
        int b = rr >> 11, ntok = rr & 2047;
        dst[(((size_t)(b * 8 + h) * N_ + ntok) << 6) + d] = f2b((acc[m][n][r] + bb) * scl);
      }
    }
  }
}

// ---------------- Kernel 4: flash attention (max-free base-2 softmax) ----------------
__launch_bounds__(256, 4)
__global__ void attn_kernel(const short* __restrict__ q, const short* __restrict__ k,
                            const short* __restrict__ v, const int* __restrict__ exist,
                            short* __restrict__ att) {
  __shared__ short Ks[64][64];    // K rows, XOR-swizzled 16B chunks
  __shared__ short VTs[64][64];   // VTs[d][pi(k)], XOR-swizzled
  __shared__ short Ps[128][64];   // Ps[q][pi(k)], XOR-swizzled
  __shared__ float Mflag[64];
  // XCD swizzle: all 16 q-blocks of one (b,h) land on the same XCD (id mod 8)
  int bx = blockIdx.x;                      // 0..1023
  int bh = ((bx >> 7) << 3) | (bx & 7);     // 0..63
  int q0 = ((bx >> 3) & 15) * 128;
  int b = bh >> 3, h = bh & 7;
  int tid = threadIdx.x, wave = tid >> 6, lane = tid & 63;
  int l16 = lane & 15, lh = lane >> 4;
  const short* qp = q + (size_t)bh * N_ * 64;
  const short* kp = k + (size_t)bh * N_ * 64;
  const short* vp = v + (size_t)bh * N_ * 64;
  const int* ex = exist + b * N_;
  v8s qf[2][2];
#pragma unroll
  for (int m = 0; m < 2; ++m)
#pragma unroll
    for (int kc = 0; kc < 2; ++kc)
      qf[m][kc] = *(const v8s*)&qp[(size_t)(q0 + wave * 32 + m * 16 + l16) * 64 + kc * 32 + lh * 8];
  f32x4 oacc[2][4] = {};
  float lsum[2][4] = {};
  for (int kt = 0; kt < N_ / 64; ++kt) {
    int kv0 = kt * 64;
    // ---- stage K: vector rows, swizzled chunks (conflict-free) ----
#pragma unroll
    for (int s = 0; s < 2; ++s) {
      int c = tid + s * 256, cr = c >> 3, cc = c & 7;
      *(v8s*)&Ks[cr][(cc ^ (cr & 7)) * 8] = *(const v8s*)&kp[(size_t)(kv0 + cr) * 64 + cc * 8];
    }
    // ---- stage V transposed+pi-permuted: dword gather + v_perm repack ----
    {
      int d0 = (tid & 31) * 2, sub = tid >> 5;   // sub 0..7
      uint dwv[8];
#pragma unroll
      for (int lo = 0; lo < 2; ++lo)
#pragma unroll
        for (int n = 0; n < 4; ++n)
          dwv[lo * 4 + n] = *(const uint*)&vp[(size_t)(kv0 + n * 16 + sub * 2 + lo) * 64 + d0];
      v8s v0c, v1c;
#pragma unroll
      for (int j = 0; j < 4; ++j) {
        uint A = dwv[2 * j], Bw = dwv[2 * j + 1];
        ((uint*)&v0c)[j] = __builtin_amdgcn_perm(Bw, A, 0x05040100u);  // lo halves (col d0)
        ((uint*)&v1c)[j] = __builtin_amdgcn_perm(Bw, A, 0x07060302u);  // hi halves (col d0+1)
      }
      *(v8s*)&VTs[d0][(sub ^ (d0 & 7)) * 8] = v0c;
      *(v8s*)&VTs[d0 + 1][(sub ^ ((d0 + 1) & 7)) * 8] = v1c;
    }
    if (tid < 64) Mflag[tid] = (ex[kv0 + tid] != 0) ? 1.f : 0.f;
    __syncthreads();
    // ---- S2 = (alpha*q) @ k^T  (base-2 exponents) ----
    f32x4 sacc[2][4] = {};
#pragma unroll
    for (int kc = 0; kc < 2; ++kc)
#pragma unroll
      for (int n = 0; n < 4; ++n) {
        int krow = n * 16 + l16;
        v8s kf = *(const v8s*)&Ks[krow][((kc * 4 + lh) ^ (krow & 7)) * 8];
#pragma unroll
        for (int m = 0; m < 2; ++m)
          sacc[m][n] = __builtin_amdgcn_mfma_f32_16x16x32_bf16(qf[m][kc], kf, sacc[m][n], 0, 0, 0);
      }
    // ---- p = 2^s2 * flag; pack to bf16 pairs; per-lane partial row-sums ----
    float flag[4];
#pragma unroll
    for (int n = 0; n < 4; ++n) flag[n] = Mflag[n * 16 + l16];
#pragma unroll
    for (int m = 0; m < 2; ++m)
#pragma unroll
      for (int r = 0; r < 4; ++r) {
        float p0 = exp2f(sacc[m][0][r]) * flag[0];
        float p1 = exp2f(sacc[m][1][r]) * flag[1];
        float p2 = exp2f(sacc[m][2][r]) * flag[2];
        float p3 = exp2f(sacc[m][3][r]) * flag[3];
        lsum[m][r] += (p0 + p1) + (p2 + p3);
        uint lopk, hipk;
        asm("v_cvt_pk_bf16_f32 %0, %1, %2" : "=v"(lopk) : "v"(p0), "v"(p1));
        asm("v_cvt_pk_bf16_f32 %0, %1, %2" : "=v"(hipk) : "v"(p2), "v"(p3));
        int row = wave * 32 + m * 16 + lh * 4 + r;
        int ch = (l16 >> 1) ^ ((lh * 4 + r) & 7);
        u32x2 pk2 = {lopk, hipk};
        *(u32x2*)((char*)Ps + row * 128 + ch * 16 + (l16 & 1) * 8) = pk2;
      }
    // ---- O += P @ V (pi-permuted k on both sides; wave-private Ps rows) ----
#pragma unroll
    for (int kc = 0; kc < 2; ++kc) {
      v8s pf[2];
#pragma unroll
      for (int m = 0; m < 2; ++m) {
        int prow = wave * 32 + m * 16 + l16;
        pf[m] = *(const v8s*)((const char*)Ps + prow * 128 + (((kc * 4 + lh) ^ (l16 & 7)) * 16));
      }
#pragma unroll
      for (int n = 0; n < 4; ++n) {
        int vrow = n * 16 + l16;
        v8s vf = *(const v8s*)&VTs[vrow][((kc * 4 + lh) ^ (vrow & 7)) * 8];
#pragma unroll
        for (int m = 0; m < 2; ++m)
          oacc[m][n] = __builtin_amdgcn_mfma_f32_16x16x32_bf16(pf[m], vf, oacc[m][n], 0, 0, 0);
      }
    }
    __syncthreads();
  }
  // ---- epilogue: deferred row-sum reduce, normalize, query-mask, write ----
#pragma unroll
  for (int m = 0; m < 2; ++m)
#pragma unroll
    for (int r = 0; r < 4; ++r) {
      float t = lsum[m][r];
      t += __shfl_xor(t, 1, 16);
      t += __shfl_xor(t, 2, 16);
      t += __shfl_xor(t, 4, 16);
      t += __shfl_xor(t, 8, 16);
      int row = q0 + wave * 32 + m * 16 + lh * 4 + r;
      float qm = (ex[row] != 0) ? 1.f : 0.f;
      float inv = qm / fmaxf(t, 1e-20f);
#pragma unroll
      for (int n = 0; n < 4; ++n)
        att[((size_t)(b * N_ + row)) * 512 + h * 64 + n * 16 + l16] = f2b(oacc[m][n][r] * inv);
    }
}

// ---------------- Kernel 5: out = att @ Wfc + bfc (M=16384, N=64, K=512), fp32 out ----------
__launch_bounds__(256)
__global__ void out_gemm(const short* __restrict__ att, const short* __restrict__ WfcT,
                         const float* __restrict__ bfc, float* __restrict__ out) {
  __shared__ short As[128][40];
  __shared__ short Bs[64][40];
  int bm = blockIdx.x;
  int tid = threadIdx.x, wave = tid >> 6, lane = tid & 63;
  int l16 = lane & 15, lh = lane >> 4;
  f32x4 acc[2][4] = {};
  for (int kt = 0; kt < 16; ++kt) {
    int k0 = kt * 32;
#pragma unroll
    for (int s = 0; s < 2; ++s) {
      int c = tid + s * 256;
      int r = c >> 2, c8 = c & 3;
      *(v8s*)&As[r][c8 * 8] = *(const v8s*)&att[(size_t)(bm * 128 + r) * 512 + k0 + c8 * 8];
    }
    { int r = tid >> 2, c8 = tid & 3;
      if (r < 64) *(v8s*)&Bs[r][c8 * 8] = *(const v8s*)&WfcT[(size_t)r * 512 + k0 + c8 * 8]; }
    __syncthreads();
    v8s bfr[4];
#pragma unroll
    for (int n = 0; n < 4; ++n) bfr[n] = *(const v8s*)&Bs[n * 16 + l16][lh * 8];
#pragma unroll
    for (int m = 0; m < 2; ++m) {
      v8s af = *(const v8s*)&As[wave * 32 + m * 16 + l16][lh * 8];
#pragma unroll
      for (int n = 0; n < 4; ++n)
        acc[m][n] = __builtin_amdgcn_mfma_f32_16x16x32_bf16(af, bfr[n], acc[m][n], 0, 0, 0);
    }
    __syncthreads();
  }
#pragma unroll
  for (int m = 0; m < 2; ++m)
#pragma unroll
    for (int n = 0; n < 4; ++n) {
      float bb = bfc[n * 16 + l16];
#pragma unroll
      for (int r = 0; r < 4; ++r) {
        int row = bm * 128 + wave * 32 + m * 16 + lh * 4 + r;
        out[(size_t)row * 64 + n * 16 + l16] = acc[m][n][r] + bb;
      }
    }
}

extern "C" void kernel_launch(void* const* d_in, const int* in_sizes, int n_in,
                              void* d_out, int out_size, void* d_ws, size_t ws_size,
                              hipStream_t stream) {
  const float* times = (const float*)d_in[0];
  const float* data  = (const float*)d_in[1];
  const float* maskv = (const float*)d_in[2];
  const int*   exist = (const int*)d_in[3];
  const float* w_per = (const float*)d_in[4];
  const float* b_per = (const float*)d_in[5];
  const float* w_lin = (const float*)d_in[6];
  const float* b_lin = (const float*)d_in[7];
  const float* Wq  = (const float*)d_in[8];
  const float* bq  = (const float*)d_in[9];
  const float* Wk  = (const float*)d_in[10];
  const float* bk  = (const float*)d_in[11];
  const float* Wv  = (const float*)d_in[12];
  const float* bv  = (const float*)d_in[13];
  const float* Wfc = (const float*)d_in[14];
  const float* bfc = (const float*)d_in[15];
  float* out = (float*)d_out;

  char* ws = (char*)d_ws;
  short* x    = (short*)(ws);                    // 16384*320*2  = 10,485,760
  short* Wt   = (short*)(ws + 10485760);         // 1536*320*2   =    983,040
  short* WfcT = (short*)(ws + 11468800);         // 64*512*2     =     65,536
  short* qb   = (short*)(ws + 11534336);         // 64*2048*64*2 = 16,777,216
  short* kb   = (short*)(ws + 28311552);
  short* vb   = (short*)(ws + 45088768);
  short* att  = (short*)(ws + 61865984);         // 16384*512*2  = 16,777,216

  build_x<<<BN, 128, 0, stream>>>(times, data, maskv, w_per, b_per, w_lin, b_lin, x);
  transpose_w<<<2048, 256, 0, stream>>>(Wq, Wk, Wv, Wfc, Wt, WfcT);
  qkv_gemm<<<dim3(128, 12), 256, 0, stream>>>(x, Wt, bq, bk, bv, qb, kb, vb);
  attn_kernel<<<1024, 256, 0, stream>>>(qb, kb, vb, exist, att);
  out_gemm<<<128, 256, 0, stream>>>(att, WfcT, bfc, out);
}